// Round 5
// baseline (544.101 us; speedup 1.0000x reference)
//
#include <hip/hip_runtime.h>
#include <hip/hip_bf16.h>
#include <cstdint>

#define BATCH 8
#define SEQ   2048
#define DIM   256
#define NN    ((size_t)SEQ * SEQ)   // 4194304 per batch
#define ND    ((size_t)SEQ * DIM)   // 524288 per batch

typedef __hip_bfloat16 bf16;
typedef __attribute__((ext_vector_type(8))) short bf16x8;
typedef __attribute__((ext_vector_type(4))) short bf16x4;
typedef __attribute__((ext_vector_type(4))) float f32x4;

__device__ __forceinline__ short bfbits(float f) {
    bf16 b = __float2bfloat16(f);
    return *reinterpret_cast<short*>(&b);
}
__device__ __forceinline__ float bf2f(short s) {
    bf16 b = *reinterpret_cast<bf16*>(&s);
    return __bfloat162float(b);
}

// async global->LDS, 16B per lane; LDS dest = wave-uniform base + lane*16
__device__ __forceinline__ void async16(const void* g, void* l) {
    __builtin_amdgcn_global_load_lds(
        (__attribute__((address_space(1))) unsigned int*)(uintptr_t)g,
        (__attribute__((address_space(3))) unsigned int*)(uintptr_t)l,
        16, 0, 0);
}

// ---------------------------------------------------------------------------
// adj [B][N][N] f32 -> adjT [B][N][N] bf16. 64x64 tile, float4 loads,
// bf16x4 (8B) stores. tile stride 67 -> <=2-way LDS banks both sides.
// ---------------------------------------------------------------------------
__global__ __launch_bounds__(256) void transpose_adj_kernel(
        const float* __restrict__ adj, bf16* __restrict__ adjT) {
    __shared__ float tile[64][67];
    const int b  = blockIdx.z;
    const int i0 = blockIdx.y << 6;
    const int j0 = blockIdx.x << 6;
    const float* src = adj + (size_t)b * NN;
    bf16* dst = adjT + (size_t)b * NN;
    const int r  = threadIdx.x >> 4;        // 0..15
    const int c4 = (threadIdx.x & 15) << 2; // 0..60 step 4
    #pragma unroll
    for (int p = 0; p < 4; ++p) {
        const int row = r + p * 16;
        const float4 v = *(const float4*)(src + (size_t)(i0 + row) * SEQ + j0 + c4);
        tile[row][c4 + 0] = v.x;
        tile[row][c4 + 1] = v.y;
        tile[row][c4 + 2] = v.z;
        tile[row][c4 + 3] = v.w;
    }
    __syncthreads();
    #pragma unroll
    for (int p = 0; p < 4; ++p) {
        const int jj = r + p * 16;
        bf16x4 o;
        o[0] = bfbits(tile[c4 + 0][jj]);
        o[1] = bfbits(tile[c4 + 1][jj]);
        o[2] = bfbits(tile[c4 + 2][jj]);
        o[3] = bfbits(tile[c4 + 3][jj]);
        *(bf16x4*)(dst + (size_t)(j0 + jj) * SEQ + i0 + c4) = o;
    }
}

// ---------------------------------------------------------------------------
// text fp32 -> bf16 (flat copy), 8 elems/thread
// ---------------------------------------------------------------------------
__global__ __launch_bounds__(256) void cast_text(
        const float* __restrict__ in, bf16* __restrict__ out) {
    const size_t i = ((size_t)blockIdx.x * 256 + threadIdx.x) * 8;
    const float4 a = *(const float4*)(in + i);
    const float4 b = *(const float4*)(in + i + 4);
    bf16x8 o;
    o[0] = bfbits(a.x); o[1] = bfbits(a.y); o[2] = bfbits(a.z); o[3] = bfbits(a.w);
    o[4] = bfbits(b.x); o[5] = bfbits(b.y); o[6] = bfbits(b.z); o[7] = bfbits(b.w);
    *(bf16x8*)(out + i) = o;
}

// ---------------------------------------------------------------------------
// W [256 in][256 out] fp32 -> WT [out][in] bf16, z selects Wq/Wk/Wv
// ---------------------------------------------------------------------------
__global__ __launch_bounds__(256) void prep_w(
        const float* __restrict__ Wq, const float* __restrict__ Wk,
        const float* __restrict__ Wv,
        bf16* __restrict__ WqT, bf16* __restrict__ WkT, bf16* __restrict__ WvT) {
    __shared__ float tile[64][65];
    const int z = blockIdx.z;
    const float* src = (z == 0) ? Wq : (z == 1) ? Wk : Wv;
    bf16* dst = (z == 0) ? WqT : (z == 1) ? WkT : WvT;
    const int i0 = blockIdx.y << 6;
    const int j0 = blockIdx.x << 6;
    const int r  = threadIdx.x >> 4;
    const int c4 = (threadIdx.x & 15) << 2;
    #pragma unroll
    for (int p = 0; p < 4; ++p) {
        const int row = r + p * 16;
        const float4 v = *(const float4*)(src + (size_t)(i0 + row) * DIM + j0 + c4);
        tile[row][c4 + 0] = v.x;
        tile[row][c4 + 1] = v.y;
        tile[row][c4 + 2] = v.z;
        tile[row][c4 + 3] = v.w;
    }
    __syncthreads();
    #pragma unroll
    for (int p = 0; p < 4; ++p) {
        const int jj = r + p * 16;
        bf16x4 o;
        o[0] = bfbits(tile[c4 + 0][jj]);
        o[1] = bfbits(tile[c4 + 1][jj]);
        o[2] = bfbits(tile[c4 + 2][jj]);
        o[3] = bfbits(tile[c4 + 3][jj]);
        *(bf16x4*)(dst + (size_t)(j0 + jj) * DIM + i0 + c4) = o;
    }
}

// ---------------------------------------------------------------------------
// Old 2-barrier 128-row GEMM, kept for the N=256 output GEMM (new_adj @ v).
// ---------------------------------------------------------------------------
template <int BM, int BN, int WR, int WC>
__global__ __launch_bounds__(256) void gemm_bt(
        const bf16* __restrict__ A, const bf16* __restrict__ Bt,
        float* __restrict__ Cf, bf16* __restrict__ Cb,
        int M, int Ncols, int K,
        long long sA, long long sB, long long sCf, long long sCb,
        float scale) {
    constexpr int FI = BM / WR / 16;
    constexpr int FJ = BN / WC / 16;
    constexpr int CA = BM / 32;
    constexpr int CB = BN / 32;

    __shared__ bf16 As[BM * 64];
    __shared__ bf16 Bs[BN * 64];
    const int bz = blockIdx.z;
    const bf16* Ab = A  + (size_t)bz * sA;
    const bf16* Bb = Bt + (size_t)bz * sB;
    const int row0 = blockIdx.x * BM;
    const int col0 = blockIdx.y * BN;
    const int tid  = threadIdx.x;
    const int wave = tid >> 6;
    const int lane = tid & 63;
    const int wr0 = (wave / WC) * (BM / WR);
    const int wc0 = (wave % WC) * (BN / WC);
    const int fl = lane & 15;
    const int fq = lane >> 4;
    const int srow = tid >> 3;
    const int sk   = ((tid & 7) ^ (srow & 7)) * 8;

    f32x4 acc[FI][FJ] = {};

    for (int k0 = 0; k0 < K; k0 += 64) {
        #pragma unroll
        for (int a = 0; a < CA; ++a)
            async16(Ab + (size_t)(row0 + a * 32 + srow) * K + k0 + sk,
                    As + a * 2048 + tid * 8);
        #pragma unroll
        for (int a = 0; a < CB; ++a)
            async16(Bb + (size_t)(col0 + a * 32 + srow) * K + k0 + sk,
                    Bs + a * 2048 + tid * 8);
        __syncthreads();
        #pragma unroll
        for (int m = 0; m < 2; ++m) {
            const int p = ((m * 4 + fq) ^ (fl & 7)) * 8;
            bf16x8 af[FI], bg[FJ];
            #pragma unroll
            for (int i = 0; i < FI; ++i)
                af[i] = *(const bf16x8*)(As + (wr0 + i * 16 + fl) * 64 + p);
            #pragma unroll
            for (int j = 0; j < FJ; ++j)
                bg[j] = *(const bf16x8*)(Bs + (wc0 + j * 16 + fl) * 64 + p);
            #pragma unroll
            for (int i = 0; i < FI; ++i)
                #pragma unroll
                for (int j = 0; j < FJ; ++j)
                    acc[i][j] = __builtin_amdgcn_mfma_f32_16x16x32_bf16(
                        af[i], bg[j], acc[i][j], 0, 0, 0);
        }
        __syncthreads();
    }

    #pragma unroll
    for (int i = 0; i < FI; ++i) {
        #pragma unroll
        for (int j = 0; j < FJ; ++j) {
            #pragma unroll
            for (int r = 0; r < 4; ++r) {
                const int row = row0 + wr0 + i * 16 + fq * 4 + r;
                const int col = col0 + wc0 + j * 16 + fl;
                const float val = acc[i][j][r] * scale;
                if (Cf) Cf[(size_t)bz * sCf + (size_t)row * Ncols + col] = val;
                if (Cb) Cb[(size_t)bz * sCb + (size_t)row * Ncols + col] =
                    __float2bfloat16(val);
            }
        }
    }
}

// ---------------------------------------------------------------------------
// 256x256-tile 8-wave 8-phase GEMM body: C = scale*(A @ Bt^T)+bias.
// A:[M][K], Bt:[Ncols][K] bf16 row-major. LDS 128KiB (proven size):
// 2 K-tile bufs x {A,B} x 2 half-tiles (128 rows x 64 k).
// EARLIEST-LEGAL staging (vs round-3): buf-X A-reads end ph3/ph7, B-reads
// end ph2/ph6 -> stage the buffer's NEXT tenant immediately after:
//   ph3: B(t+2)h0 | ph4: B(t+2)h1 + A(t+2)h0 + A(t+2)h1
//   ph7: B(t+3)h0 | ph8: B(t+3)h1 + A(t+3)h0 + A(t+3)h1
// -> min prefetch distance 5 phases (~1000cy) vs round-3's 3 (~600cy).
// vmcnt ledger (2 loads/stage-unit): prologue stages t0+t1 (16), VM8
// leaves t1's 8. Steady: enter iter with next tile's 8; ph3/ph4 (+8) -> 16;
// VM8 drains the 8 oldest = the tile about to be read. Symmetric at ph8.
// Clamped tail stages hit dead-or-identical data, always after the barrier
// ending that buffer's reads. NT even, >=2.
// transC: write Cb transposed into vT[b][o][n] ([8][256][2048] hardcoded).
// ---------------------------------------------------------------------------
__device__ __forceinline__ void gemm256_body(
        const bf16* __restrict__ Ab, const bf16* __restrict__ Bb,
        float* __restrict__ Cf, bf16* __restrict__ Cb,
        int Ncols, int K, int row0, int col0, float scale,
        const float* __restrict__ bias, int transC) {
    __shared__ bf16 As[2][2][8192];   // [buf][half][128*64]
    __shared__ bf16 Bs[2][2][8192];

    const int tid  = threadIdx.x;
    const int wave = tid >> 6;
    const int lane = tid & 63;
    const int wm = wave >> 2;         // 0..1 -> A half / 128-row block
    const int wn = wave & 3;          // 0..3 -> 64-col block
    const int fl = lane & 15;
    const int fq = lane >> 4;

    const int NT = K >> 6;            // K-tiles of 64 (even, >=2)

    int aoff[2], boff[2];
    #pragma unroll
    for (int m = 0; m < 2; ++m) {
        const int c = ((m * 4 + fq) ^ (fl & 7)) * 8;
        aoff[m] = fl * 64 + c;
        boff[m] = ((wn & 1) * 64 + fl) * 64 + c;
    }

    auto stageA = [&](int buf, int h, int tt) {
        const bf16* g = Ab + (size_t)(row0 + h * 128) * K + tt * 64;
        #pragma unroll
        for (int q = 0; q < 2; ++q) {
            const int idx = q * 512 + tid;
            const int r = idx >> 3;
            const int gk = ((idx & 7) ^ (r & 7)) * 8;
            async16(g + (size_t)r * K + gk, &As[buf][h][idx * 8]);
        }
    };
    auto stageB = [&](int buf, int h, int tt) {
        const bf16* g = Bb + (size_t)(col0 + h * 128) * K + tt * 64;
        #pragma unroll
        for (int q = 0; q < 2; ++q) {
            const int idx = q * 512 + tid;
            const int r = idx >> 3;
            const int gk = ((idx & 7) ^ (r & 7)) * 8;
            async16(g + (size_t)r * K + gk, &Bs[buf][h][idx * 8]);
        }
    };

    f32x4 acc[8][4] = {};
    bf16x8 af[4][2], b01[2][2], b23[2][2];

#define LOADA(buf, ib) do {                                                   \
    const bf16* _s = &As[buf][wm][0];                                         \
    _Pragma("unroll") for (int i = 0; i < 4; ++i)                             \
      _Pragma("unroll") for (int m = 0; m < 2; ++m)                           \
        af[i][m] = *(const bf16x8*)(_s + ((ib) + i) * 1024 + aoff[m]);        \
} while (0)
#define LOADB(buf, dst, jb) do {                                              \
    const bf16* _s = &Bs[buf][wn >> 1][0];                                    \
    _Pragma("unroll") for (int j = 0; j < 2; ++j)                             \
      _Pragma("unroll") for (int m = 0; m < 2; ++m)                           \
        dst[j][m] = *(const bf16x8*)(_s + ((jb) + j) * 1024 + boff[m]);       \
} while (0)
#define MFMA_Q(IB, BB, JB) do {                                               \
    __builtin_amdgcn_s_setprio(1);                                            \
    _Pragma("unroll") for (int m = 0; m < 2; ++m)                             \
      _Pragma("unroll") for (int i = 0; i < 4; ++i)                           \
        _Pragma("unroll") for (int j = 0; j < 2; ++j)                         \
            acc[(IB) + i][(JB) + j] = __builtin_amdgcn_mfma_f32_16x16x32_bf16(\
                af[i][m], BB[j][m], acc[(IB) + i][(JB) + j], 0, 0, 0);        \
    __builtin_amdgcn_s_setprio(0);                                            \
} while (0)
#define SBAR  __builtin_amdgcn_s_barrier()
#define LGKM0 asm volatile("s_waitcnt lgkmcnt(0)" ::: "memory")
#define VM8   asm volatile("s_waitcnt vmcnt(8)" ::: "memory")

    // prologue: stage t0 fully, then t1 fully; VM8 drains t0, t1 in flight.
    stageA(0, 0, 0); stageA(0, 1, 0); stageB(0, 0, 0); stageB(0, 1, 0);
    stageB(1, 0, 1); stageB(1, 1, 1); stageA(1, 0, 1); stageA(1, 1, 1);
    VM8;
    SBAR;

    for (int t = 0; t < NT; t += 2) {
        const int t2 = (t + 2 < NT) ? t + 2 : NT - 1;   // clamped prefetch
        const int t3 = (t + 3 < NT) ? t + 3 : NT - 1;
        // ---- K-tile t (buf0) ----
        // phase 1: quadrant (i0-3, j0-1)
        LOADA(0, 0); LOADB(0, b01, 0);
        SBAR; LGKM0; MFMA_Q(0, b01, 0); SBAR;
        // phase 2: (i0-3, j2-3)
        LOADB(0, b23, 2);
        SBAR; LGKM0; MFMA_Q(0, b23, 2); SBAR;
        // phase 3: (i4-7, j2-3)   [buf0 B reads done ph2 -> stage t2 B h0]
        LOADA(0, 4);
        stageB(0, 0, t2);
        SBAR; LGKM0; MFMA_Q(4, b23, 2); SBAR;
        // phase 4: (i4-7, j0-1)   [buf0 A reads done ph3 -> stage t2 rest]
        stageB(0, 1, t2);
        stageA(0, 0, t2); stageA(0, 1, t2);
        SBAR; MFMA_Q(4, b01, 0);
        VM8;        // drains t+1's 8; leaves t+2's 8 in flight
        SBAR;
        // ---- K-tile t+1 (buf1) ----
        // phase 5
        LOADA(1, 0); LOADB(1, b01, 0);
        SBAR; LGKM0; MFMA_Q(0, b01, 0); SBAR;
        // phase 6
        LOADB(1, b23, 2);
        SBAR; LGKM0; MFMA_Q(0, b23, 2); SBAR;
        // phase 7   [buf1 B reads done ph6 -> stage t3 B h0]
        LOADA(1, 4);
        stageB(1, 0, t3);
        SBAR; LGKM0; MFMA_Q(4, b23, 2); SBAR;
        // phase 8   [buf1 A reads done ph7 -> stage t3 rest]
        stageB(1, 1, t3);
        stageA(1, 0, t3); stageA(1, 1, t3);
        SBAR; MFMA_Q(4, b01, 0);
        VM8;        // drains t+2's 8; leaves t+3's 8 in flight
        SBAR;
    }

    // drain tail prefetches before epilogue / endpgm
    asm volatile("s_waitcnt vmcnt(0)" ::: "memory");
    SBAR;

#undef LOADA
#undef LOADB
#undef MFMA_Q
#undef SBAR
#undef LGKM0
#undef VM8

    // C/D layout: col = lane&15, row = (lane>>4)*4 + reg
    #pragma unroll
    for (int i = 0; i < 8; ++i) {
        #pragma unroll
        for (int j = 0; j < 4; ++j) {
            const int rowb = row0 + wm * 128 + i * 16 + fq * 4;
            const int col  = col0 + wn * 64 + j * 16 + fl;
            const float badd = bias ? bias[col] : 0.0f;
            if (transC) {
                // vT[b][o][n] = [8][256][2048]; rowb..rowb+3 within one batch
                bf16x4 o;
                #pragma unroll
                for (int r = 0; r < 4; ++r)
                    o[r] = bfbits(acc[i][j][r] * scale + badd);
                *(bf16x4*)(Cb + (size_t)(rowb >> 11) * ND +
                           (size_t)col * SEQ + (rowb & 2047)) = o;
            } else {
                #pragma unroll
                for (int r = 0; r < 4; ++r) {
                    const int row = rowb + r;
                    const float val = acc[i][j][r] * scale + badd;
                    if (Cf) Cf[(size_t)row * Ncols + col] = val;
                    if (Cb) Cb[(size_t)row * Ncols + col] = __float2bfloat16(val);
                }
            }
        }
    }
}

// ---------------------------------------------------------------------------
// batched square-GEMM wrapper with XCD-bijective tile swizzle
// ---------------------------------------------------------------------------
__global__ __launch_bounds__(512, 2) void gemm256(
        const bf16* __restrict__ A, const bf16* __restrict__ Bt,
        float* __restrict__ Cf, bf16* __restrict__ Cb,
        int M, int Ncols, int K,
        long long sA, long long sB, long long sCf, long long sCb,
        float scale) {
    (void)M;
    const int bz = blockIdx.z;
    const int gx = gridDim.x, gy = gridDim.y;
    const int nwg = gx * gy;
    int lwg = blockIdx.x + blockIdx.y * gx;
    int swz = lwg;
    if ((nwg & 7) == 0) swz = (lwg & 7) * (nwg >> 3) + (lwg >> 3);
    const int row0 = (swz % gx) * 256;
    const int col0 = (swz / gx) * 256;
    gemm256_body(A + (size_t)bz * sA, Bt + (size_t)bz * sB,
                 Cf ? Cf + (size_t)bz * sCf : nullptr,
                 Cb ? Cb + (size_t)bz * sCb : nullptr,
                 Ncols, K, row0, col0, scale, nullptr, 0);
}

// ---------------------------------------------------------------------------
// fused QKV projection: z selects {Wq,Wk,Wv}; v written transposed to vT.
// A = textb [16384][256] bf16; WT = [256 out][256 in] bf16.
// ---------------------------------------------------------------------------
__global__ __launch_bounds__(512, 2) void qkv256(
        const bf16* __restrict__ textb,
        const bf16* __restrict__ WqT, const bf16* __restrict__ WkT,
        const bf16* __restrict__ WvT,
        const float* __restrict__ bq, const float* __restrict__ bk,
        const float* __restrict__ bv,
        bf16* __restrict__ q, bf16* __restrict__ k, bf16* __restrict__ vT) {
    const int x = blockIdx.x;                       // 0..63
    const int swz = (x & 7) * 8 + (x >> 3);         // XCD swizzle (64 wgs)
    const int row0 = swz * 256;
    const int z = blockIdx.z;
    const bf16* W = (z == 0) ? WqT : (z == 1) ? WkT : WvT;
    const float* bias = (z == 0) ? bq : (z == 1) ? bk : bv;
    bf16* out = (z == 0) ? q : (z == 1) ? k : vT;
    gemm256_body(textb, W, nullptr, out, DIM, DIM, row0, 0, 1.0f,
                 bias, (z == 2) ? 1 : 0);
}

// ---------------------------------------------------------------------------
// in-place row softmax, bf16 rows of length SEQ; 16B vector load/store
// ---------------------------------------------------------------------------
__global__ __launch_bounds__(256) void softmax_rows(bf16* __restrict__ S) {
    __shared__ float red[4];
    bf16* p = S + (size_t)blockIdx.x * SEQ;
    const int t = threadIdx.x;
    bf16x8 v8 = *(const bf16x8*)(p + t * 8);
    float x[8];
    #pragma unroll
    for (int j = 0; j < 8; ++j) x[j] = bf2f(v8[j]);
    float m = x[0];
    #pragma unroll
    for (int j = 1; j < 8; ++j) m = fmaxf(m, x[j]);
    #pragma unroll
    for (int off = 32; off >= 1; off >>= 1) m = fmaxf(m, __shfl_xor(m, off, 64));
    if ((t & 63) == 0) red[t >> 6] = m;
    __syncthreads();
    m = fmaxf(fmaxf(red[0], red[1]), fmaxf(red[2], red[3]));
    __syncthreads();
    float s = 0.f;
    #pragma unroll
    for (int j = 0; j < 8; ++j) { x[j] = __expf(x[j] - m); s += x[j]; }
    #pragma unroll
    for (int off = 32; off >= 1; off >>= 1) s += __shfl_xor(s, off, 64);
    if ((t & 63) == 0) red[t >> 6] = s;
    __syncthreads();
    s = red[0] + red[1] + red[2] + red[3];
    const float inv = 1.0f / s;
    bf16x8 o8;
    #pragma unroll
    for (int j = 0; j < 8; ++j) o8[j] = bfbits(x[j] * inv);
    *(bf16x8*)(p + t * 8) = o8;
}

// ---------------------------------------------------------------------------
extern "C" void kernel_launch(void* const* d_in, const int* in_sizes, int n_in,
                              void* d_out, int out_size, void* d_ws, size_t ws_size,
                              hipStream_t stream) {
    (void)in_sizes; (void)n_in; (void)out_size; (void)ws_size;
    const float* text = (const float*)d_in[0];
    const float* adj  = (const float*)d_in[1];
    const float* Wq   = (const float*)d_in[2];
    const float* bq   = (const float*)d_in[3];
    const float* Wk   = (const float*)d_in[4];
    const float* bk   = (const float*)d_in[5];
    const float* Wv   = (const float*)d_in[6];
    const float* bv   = (const float*)d_in[7];

    float* out0 = (float*)d_out;                 // output [B,N,D]
    float* out1 = out0 + (size_t)BATCH * ND;     // new_adj [B,N,N]

    bf16* w = (bf16*)d_ws;
    bf16* adjT = w;  w += BATCH * NN;
    bf16* qb   = w;  w += BATCH * ND;
    bf16* kb   = w;  w += BATCH * ND;
    bf16* vTb  = w;  w += BATCH * ND;   // [B][D][N]
    bf16* attn = w;  w += BATCH * NN;   // scores, then softmax in place
    bf16* nadj = w;  w += BATCH * NN;

    // textb + WT alias the head of nadj (dead until the attn@adj GEMM)
    bf16* textb = nadj;                     // [16384][256] bf16 = 8.4 MB
    bf16* WqT = nadj + BATCH * ND;          // 3 x [256][256] bf16
    bf16* WkT = WqT + DIM * DIM;
    bf16* WvT = WkT + DIM * DIM;

    transpose_adj_kernel<<<dim3(32, 32, BATCH), 256, 0, stream>>>(adj, adjT);
    cast_text<<<dim3(BATCH * SEQ * DIM / 2048), 256, 0, stream>>>(text, textb);
    prep_w<<<dim3(4, 4, 3), 256, 0, stream>>>(Wq, Wk, Wv, WqT, WkT, WvT);
    // q/k row-major bf16, v transposed -> vT[b][o][n]; bias fused
    qkv256<<<dim3(64, 1, 3), 512, 0, stream>>>(
        textb, WqT, WkT, WvT, bq, bk, bv, qb, kb, vTb);
    // scores = (q @ k^T) / 16  -> bf16
    gemm256<<<dim3(SEQ / 256, SEQ / 256, BATCH), 512, 0, stream>>>(
        qb, kb, nullptr, attn, SEQ, SEQ, DIM,
        (long long)ND, (long long)ND, 0, (long long)NN, 1.0f / 16.0f);
    softmax_rows<<<dim3(BATCH * SEQ), 256, 0, stream>>>(attn);
    // new_adj = attn @ adj  -> fp32 (d_out) + bf16 (ws)
    gemm256<<<dim3(SEQ / 256, SEQ / 256, BATCH), 512, 0, stream>>>(
        attn, adjT, out1, nadj, SEQ, SEQ, SEQ,
        (long long)NN, (long long)NN, (long long)NN, (long long)NN, 1.0f);
    // output = new_adj @ v  -> fp32 (d_out); 128x64 tile => 512 blocks
    gemm_bt<128, 64, 4, 1><<<dim3(16, 4, BATCH), 256, 0, stream>>>(
        nadj, vTb, out0, nullptr, SEQ, DIM, SEQ,
        (long long)NN, (long long)ND, (long long)ND, 0, 1.0f);
}

// Round 6
// 541.223 us; speedup vs baseline: 1.0053x; 1.0053x over previous
//
#include <hip/hip_runtime.h>
#include <hip/hip_bf16.h>
#include <cstdint>

#define BATCH 8
#define SEQ   2048
#define DIM   256
#define NN    ((size_t)SEQ * SEQ)   // 4194304 per batch
#define ND    ((size_t)SEQ * DIM)   // 524288 per batch

typedef __hip_bfloat16 bf16;
typedef __attribute__((ext_vector_type(8))) short bf16x8;
typedef __attribute__((ext_vector_type(4))) short bf16x4;
typedef __attribute__((ext_vector_type(4))) float f32x4;

__device__ __forceinline__ short bfbits(float f) {
    bf16 b = __float2bfloat16(f);
    return *reinterpret_cast<short*>(&b);
}
__device__ __forceinline__ float bf2f(short s) {
    bf16 b = *reinterpret_cast<bf16*>(&s);
    return __bfloat162float(b);
}

// async global->LDS, 16B per lane; LDS dest = wave-uniform base + lane*16
__device__ __forceinline__ void async16(const void* g, void* l) {
    __builtin_amdgcn_global_load_lds(
        (__attribute__((address_space(1))) unsigned int*)(uintptr_t)g,
        (__attribute__((address_space(3))) unsigned int*)(uintptr_t)l,
        16, 0, 0);
}

// ---------------------------------------------------------------------------
// adj [B][N][N] f32 -> adjT [B][N][N] bf16. 64x64 tile, float4 loads,
// bf16x4 (8B) stores. tile stride 67 -> <=2-way LDS banks both sides.
// ---------------------------------------------------------------------------
__global__ __launch_bounds__(256) void transpose_adj_kernel(
        const float* __restrict__ adj, bf16* __restrict__ adjT) {
    __shared__ float tile[64][67];
    const int b  = blockIdx.z;
    const int i0 = blockIdx.y << 6;
    const int j0 = blockIdx.x << 6;
    const float* src = adj + (size_t)b * NN;
    bf16* dst = adjT + (size_t)b * NN;
    const int r  = threadIdx.x >> 4;        // 0..15
    const int c4 = (threadIdx.x & 15) << 2; // 0..60 step 4
    #pragma unroll
    for (int p = 0; p < 4; ++p) {
        const int row = r + p * 16;
        const float4 v = *(const float4*)(src + (size_t)(i0 + row) * SEQ + j0 + c4);
        tile[row][c4 + 0] = v.x;
        tile[row][c4 + 1] = v.y;
        tile[row][c4 + 2] = v.z;
        tile[row][c4 + 3] = v.w;
    }
    __syncthreads();
    #pragma unroll
    for (int p = 0; p < 4; ++p) {
        const int jj = r + p * 16;
        bf16x4 o;
        o[0] = bfbits(tile[c4 + 0][jj]);
        o[1] = bfbits(tile[c4 + 1][jj]);
        o[2] = bfbits(tile[c4 + 2][jj]);
        o[3] = bfbits(tile[c4 + 3][jj]);
        *(bf16x4*)(dst + (size_t)(j0 + jj) * SEQ + i0 + c4) = o;
    }
}

// ---------------------------------------------------------------------------
// text fp32 -> bf16 (flat copy), 8 elems/thread
// ---------------------------------------------------------------------------
__global__ __launch_bounds__(256) void cast_text(
        const float* __restrict__ in, bf16* __restrict__ out) {
    const size_t i = ((size_t)blockIdx.x * 256 + threadIdx.x) * 8;
    const float4 a = *(const float4*)(in + i);
    const float4 b = *(const float4*)(in + i + 4);
    bf16x8 o;
    o[0] = bfbits(a.x); o[1] = bfbits(a.y); o[2] = bfbits(a.z); o[3] = bfbits(a.w);
    o[4] = bfbits(b.x); o[5] = bfbits(b.y); o[6] = bfbits(b.z); o[7] = bfbits(b.w);
    *(bf16x8*)(out + i) = o;
}

// ---------------------------------------------------------------------------
// W [256 in][256 out] fp32 -> WT [out][in] bf16, z selects Wq/Wk/Wv
// ---------------------------------------------------------------------------
__global__ __launch_bounds__(256) void prep_w(
        const float* __restrict__ Wq, const float* __restrict__ Wk,
        const float* __restrict__ Wv,
        bf16* __restrict__ WqT, bf16* __restrict__ WkT, bf16* __restrict__ WvT) {
    __shared__ float tile[64][65];
    const int z = blockIdx.z;
    const float* src = (z == 0) ? Wq : (z == 1) ? Wk : Wv;
    bf16* dst = (z == 0) ? WqT : (z == 1) ? WkT : WvT;
    const int i0 = blockIdx.y << 6;
    const int j0 = blockIdx.x << 6;
    const int r  = threadIdx.x >> 4;
    const int c4 = (threadIdx.x & 15) << 2;
    #pragma unroll
    for (int p = 0; p < 4; ++p) {
        const int row = r + p * 16;
        const float4 v = *(const float4*)(src + (size_t)(i0 + row) * DIM + j0 + c4);
        tile[row][c4 + 0] = v.x;
        tile[row][c4 + 1] = v.y;
        tile[row][c4 + 2] = v.z;
        tile[row][c4 + 3] = v.w;
    }
    __syncthreads();
    #pragma unroll
    for (int p = 0; p < 4; ++p) {
        const int jj = r + p * 16;
        bf16x4 o;
        o[0] = bfbits(tile[c4 + 0][jj]);
        o[1] = bfbits(tile[c4 + 1][jj]);
        o[2] = bfbits(tile[c4 + 2][jj]);
        o[3] = bfbits(tile[c4 + 3][jj]);
        *(bf16x4*)(dst + (size_t)(j0 + jj) * DIM + i0 + c4) = o;
    }
}

// ---------------------------------------------------------------------------
// 2-barrier 128x128 GEMM, used for the N=256 output GEMM (new_adj @ v).
// grid (16,2,8) = 256 blocks -> exactly 1 block/CU, A re-read 2x (was 4x).
// ---------------------------------------------------------------------------
template <int BM, int BN, int WR, int WC>
__global__ __launch_bounds__(256) void gemm_bt(
        const bf16* __restrict__ A, const bf16* __restrict__ Bt,
        float* __restrict__ Cf, bf16* __restrict__ Cb,
        int M, int Ncols, int K,
        long long sA, long long sB, long long sCf, long long sCb,
        float scale) {
    constexpr int FI = BM / WR / 16;
    constexpr int FJ = BN / WC / 16;
    constexpr int CA = BM / 32;
    constexpr int CB = BN / 32;

    __shared__ bf16 As[BM * 64];
    __shared__ bf16 Bs[BN * 64];
    const int bz = blockIdx.z;
    const bf16* Ab = A  + (size_t)bz * sA;
    const bf16* Bb = Bt + (size_t)bz * sB;
    const int row0 = blockIdx.x * BM;
    const int col0 = blockIdx.y * BN;
    const int tid  = threadIdx.x;
    const int wave = tid >> 6;
    const int lane = tid & 63;
    const int wr0 = (wave / WC) * (BM / WR);
    const int wc0 = (wave % WC) * (BN / WC);
    const int fl = lane & 15;
    const int fq = lane >> 4;
    const int srow = tid >> 3;
    const int sk   = ((tid & 7) ^ (srow & 7)) * 8;

    f32x4 acc[FI][FJ] = {};

    for (int k0 = 0; k0 < K; k0 += 64) {
        #pragma unroll
        for (int a = 0; a < CA; ++a)
            async16(Ab + (size_t)(row0 + a * 32 + srow) * K + k0 + sk,
                    As + a * 2048 + tid * 8);
        #pragma unroll
        for (int a = 0; a < CB; ++a)
            async16(Bb + (size_t)(col0 + a * 32 + srow) * K + k0 + sk,
                    Bs + a * 2048 + tid * 8);
        __syncthreads();
        #pragma unroll
        for (int m = 0; m < 2; ++m) {
            const int p = ((m * 4 + fq) ^ (fl & 7)) * 8;
            bf16x8 af[FI], bg[FJ];
            #pragma unroll
            for (int i = 0; i < FI; ++i)
                af[i] = *(const bf16x8*)(As + (wr0 + i * 16 + fl) * 64 + p);
            #pragma unroll
            for (int j = 0; j < FJ; ++j)
                bg[j] = *(const bf16x8*)(Bs + (wc0 + j * 16 + fl) * 64 + p);
            #pragma unroll
            for (int i = 0; i < FI; ++i)
                #pragma unroll
                for (int j = 0; j < FJ; ++j)
                    acc[i][j] = __builtin_amdgcn_mfma_f32_16x16x32_bf16(
                        af[i], bg[j], acc[i][j], 0, 0, 0);
        }
        __syncthreads();
    }

    #pragma unroll
    for (int i = 0; i < FI; ++i) {
        #pragma unroll
        for (int j = 0; j < FJ; ++j) {
            #pragma unroll
            for (int r = 0; r < 4; ++r) {
                const int row = row0 + wr0 + i * 16 + fq * 4 + r;
                const int col = col0 + wc0 + j * 16 + fl;
                const float val = acc[i][j][r] * scale;
                if (Cf) Cf[(size_t)bz * sCf + (size_t)row * Ncols + col] = val;
                if (Cb) Cb[(size_t)bz * sCb + (size_t)row * Ncols + col] =
                    __float2bfloat16(val);
            }
        }
    }
}

// ---------------------------------------------------------------------------
// 256x256-tile 8-wave 8-phase GEMM body (ROUND-3 SCHEDULE, measured 155us on
// the K=2048 dispatch): C = scale*(A @ Bt^T)+bias.
// A:[M][K], Bt:[Ncols][K] bf16 row-major. LDS 128KiB:
// 2 K-tile bufs x {A,B} x 2 half-tiles (128 rows x 64 k).
// Staging SPREAD one call per phase (burst-issue at ph4/8 measured -12%
// in round 5 -- do not cluster). Counted vmcnt(4) at phases 4/8 only.
// vmcnt ledger (2 loads/stage call): prologue 12 issued, VM4 leaves t1's
// B pair; each half-iter issues 8 / VM4 drains 8 -> buffer about to be
// ds_read always landed at the barrier after VM4. NT even, >=2.
// transC: write Cb transposed into vT[b][o][n] ([8][256][2048] hardcoded).
// ---------------------------------------------------------------------------
__device__ __forceinline__ void gemm256_body(
        const bf16* __restrict__ Ab, const bf16* __restrict__ Bb,
        float* __restrict__ Cf, bf16* __restrict__ Cb,
        int Ncols, int K, int row0, int col0, float scale,
        const float* __restrict__ bias, int transC) {
    __shared__ bf16 As[2][2][8192];   // [buf][half][128*64]
    __shared__ bf16 Bs[2][2][8192];

    const int tid  = threadIdx.x;
    const int wave = tid >> 6;
    const int lane = tid & 63;
    const int wm = wave >> 2;         // 0..1 -> A half / 128-row block
    const int wn = wave & 3;          // 0..3 -> 64-col block
    const int fl = lane & 15;
    const int fq = lane >> 4;

    const int NT = K >> 6;            // K-tiles of 64 (even, >=2)

    int aoff[2], boff[2];
    #pragma unroll
    for (int m = 0; m < 2; ++m) {
        const int c = ((m * 4 + fq) ^ (fl & 7)) * 8;
        aoff[m] = fl * 64 + c;
        boff[m] = ((wn & 1) * 64 + fl) * 64 + c;
    }

    auto stageA = [&](int buf, int h, int tt) {
        const bf16* g = Ab + (size_t)(row0 + h * 128) * K + tt * 64;
        #pragma unroll
        for (int q = 0; q < 2; ++q) {
            const int idx = q * 512 + tid;
            const int r = idx >> 3;
            const int gk = ((idx & 7) ^ (r & 7)) * 8;
            async16(g + (size_t)r * K + gk, &As[buf][h][idx * 8]);
        }
    };
    auto stageB = [&](int buf, int h, int tt) {
        const bf16* g = Bb + (size_t)(col0 + h * 128) * K + tt * 64;
        #pragma unroll
        for (int q = 0; q < 2; ++q) {
            const int idx = q * 512 + tid;
            const int r = idx >> 3;
            const int gk = ((idx & 7) ^ (r & 7)) * 8;
            async16(g + (size_t)r * K + gk, &Bs[buf][h][idx * 8]);
        }
    };

    f32x4 acc[8][4] = {};
    bf16x8 af[4][2], b01[2][2], b23[2][2];

#define LOADA(buf, ib) do {                                                   \
    const bf16* _s = &As[buf][wm][0];                                         \
    _Pragma("unroll") for (int i = 0; i < 4; ++i)                             \
      _Pragma("unroll") for (int m = 0; m < 2; ++m)                           \
        af[i][m] = *(const bf16x8*)(_s + ((ib) + i) * 1024 + aoff[m]);        \
} while (0)
#define LOADB(buf, dst, jb) do {                                              \
    const bf16* _s = &Bs[buf][wn >> 1][0];                                    \
    _Pragma("unroll") for (int j = 0; j < 2; ++j)                             \
      _Pragma("unroll") for (int m = 0; m < 2; ++m)                           \
        dst[j][m] = *(const bf16x8*)(_s + ((jb) + j) * 1024 + boff[m]);       \
} while (0)
#define MFMA_Q(IB, BB, JB) do {                                               \
    __builtin_amdgcn_s_setprio(1);                                            \
    _Pragma("unroll") for (int m = 0; m < 2; ++m)                             \
      _Pragma("unroll") for (int i = 0; i < 4; ++i)                           \
        _Pragma("unroll") for (int j = 0; j < 2; ++j)                         \
            acc[(IB) + i][(JB) + j] = __builtin_amdgcn_mfma_f32_16x16x32_bf16(\
                af[i][m], BB[j][m], acc[(IB) + i][(JB) + j], 0, 0, 0);        \
    __builtin_amdgcn_s_setprio(0);                                            \
} while (0)
#define SBAR  __builtin_amdgcn_s_barrier()
#define LGKM0 asm volatile("s_waitcnt lgkmcnt(0)" ::: "memory")
#define VM4   asm volatile("s_waitcnt vmcnt(4)" ::: "memory")

    // prologue: buf0 <- t0 (all 4 halves), buf1 <- t1 B halves.
    stageA(0, 0, 0); stageA(0, 1, 0); stageB(0, 0, 0); stageB(0, 1, 0);
    stageB(1, 0, 1); stageB(1, 1, 1);
    VM4;            // t0 fully landed; t1's B pair (4 loads) stays in flight
    SBAR;

    for (int t = 0; t < NT; t += 2) {
        const int t2 = (t + 2 < NT) ? t + 2 : NT - 1;   // clamped prefetch
        const int t3 = (t + 3 < NT) ? t + 3 : NT - 1;
        // ---- K-tile t (buf0) ----
        LOADA(0, 0); LOADB(0, b01, 0);
        stageA(1, 0, t + 1);
        SBAR; LGKM0; MFMA_Q(0, b01, 0); SBAR;
        LOADB(0, b23, 2);
        stageA(1, 1, t + 1);
        SBAR; LGKM0; MFMA_Q(0, b23, 2); SBAR;
        LOADA(0, 4);
        stageB(0, 0, t2);
        SBAR; LGKM0; MFMA_Q(4, b23, 2); SBAR;
        stageB(0, 1, t2);
        SBAR; MFMA_Q(4, b01, 0);
        VM4;        // completes t1's 4 half-tiles; t2 B pair stays in flight
        SBAR;
        // ---- K-tile t+1 (buf1) ----
        LOADA(1, 0); LOADB(1, b01, 0);
        stageA(0, 0, t2);
        SBAR; LGKM0; MFMA_Q(0, b01, 0); SBAR;
        LOADB(1, b23, 2);
        stageA(0, 1, t2);
        SBAR; LGKM0; MFMA_Q(0, b23, 2); SBAR;
        LOADA(1, 4);
        stageB(1, 0, t3);
        SBAR; LGKM0; MFMA_Q(4, b23, 2); SBAR;
        stageB(1, 1, t3);
        SBAR; MFMA_Q(4, b01, 0);
        VM4;        // completes t2's 4 half-tiles; t3 B pair stays in flight
        SBAR;
    }

    // drain tail prefetches before epilogue / endpgm
    asm volatile("s_waitcnt vmcnt(0)" ::: "memory");
    SBAR;

#undef LOADA
#undef LOADB
#undef MFMA_Q
#undef SBAR
#undef LGKM0
#undef VM4

    // C/D layout: col = lane&15, row = (lane>>4)*4 + reg
    #pragma unroll
    for (int i = 0; i < 8; ++i) {
        #pragma unroll
        for (int j = 0; j < 4; ++j) {
            const int rowb = row0 + wm * 128 + i * 16 + fq * 4;
            const int col  = col0 + wn * 64 + j * 16 + fl;
            const float badd = bias ? bias[col] : 0.0f;
            if (transC) {
                // vT[b][o][n] = [8][256][2048]; rowb..rowb+3 within one batch
                bf16x4 o;
                #pragma unroll
                for (int r = 0; r < 4; ++r)
                    o[r] = bfbits(acc[i][j][r] * scale + badd);
                *(bf16x4*)(Cb + (size_t)(rowb >> 11) * ND +
                           (size_t)col * SEQ + (rowb & 2047)) = o;
            } else {
                #pragma unroll
                for (int r = 0; r < 4; ++r) {
                    const int row = rowb + r;
                    const float val = acc[i][j][r] * scale + badd;
                    if (Cf) Cf[(size_t)row * Ncols + col] = val;
                    if (Cb) Cb[(size_t)row * Ncols + col] = __float2bfloat16(val);
                }
            }
        }
    }
}

// ---------------------------------------------------------------------------
// batched square-GEMM wrapper with XCD-bijective tile swizzle
// ---------------------------------------------------------------------------
__global__ __launch_bounds__(512, 2) void gemm256(
        const bf16* __restrict__ A, const bf16* __restrict__ Bt,
        float* __restrict__ Cf, bf16* __restrict__ Cb,
        int M, int Ncols, int K,
        long long sA, long long sB, long long sCf, long long sCb,
        float scale) {
    (void)M;
    const int bz = blockIdx.z;
    const int gx = gridDim.x, gy = gridDim.y;
    const int nwg = gx * gy;
    int lwg = blockIdx.x + blockIdx.y * gx;
    int swz = lwg;
    if ((nwg & 7) == 0) swz = (lwg & 7) * (nwg >> 3) + (lwg >> 3);
    const int row0 = (swz % gx) * 256;
    const int col0 = (swz / gx) * 256;
    gemm256_body(A + (size_t)bz * sA, Bt + (size_t)bz * sB,
                 Cf ? Cf + (size_t)bz * sCf : nullptr,
                 Cb ? Cb + (size_t)bz * sCb : nullptr,
                 Ncols, K, row0, col0, scale, nullptr, 0);
}

// ---------------------------------------------------------------------------
// fused QKV projection: z selects {Wq,Wk,Wv}; v written transposed to vT.
// A = textb [16384][256] bf16; WT = [256 out][256 in] bf16.
// ---------------------------------------------------------------------------
__global__ __launch_bounds__(512, 2) void qkv256(
        const bf16* __restrict__ textb,
        const bf16* __restrict__ WqT, const bf16* __restrict__ WkT,
        const bf16* __restrict__ WvT,
        const float* __restrict__ bq, const float* __restrict__ bk,
        const float* __restrict__ bv,
        bf16* __restrict__ q, bf16* __restrict__ k, bf16* __restrict__ vT) {
    const int x = blockIdx.x;                       // 0..63
    const int swz = (x & 7) * 8 + (x >> 3);         // XCD swizzle (64 wgs)
    const int row0 = swz * 256;
    const int z = blockIdx.z;
    const bf16* W = (z == 0) ? WqT : (z == 1) ? WkT : WvT;
    const float* bias = (z == 0) ? bq : (z == 1) ? bk : bv;
    bf16* out = (z == 0) ? q : (z == 1) ? k : vT;
    gemm256_body(textb, W, nullptr, out, DIM, DIM, row0, 0, 1.0f,
                 bias, (z == 2) ? 1 : 0);
}

// ---------------------------------------------------------------------------
// in-place row softmax, bf16 rows of length SEQ; 16B vector load/store
// ---------------------------------------------------------------------------
__global__ __launch_bounds__(256) void softmax_rows(bf16* __restrict__ S) {
    __shared__ float red[4];
    bf16* p = S + (size_t)blockIdx.x * SEQ;
    const int t = threadIdx.x;
    bf16x8 v8 = *(const bf16x8*)(p + t * 8);
    float x[8];
    #pragma unroll
    for (int j = 0; j < 8; ++j) x[j] = bf2f(v8[j]);
    float m = x[0];
    #pragma unroll
    for (int j = 1; j < 8; ++j) m = fmaxf(m, x[j]);
    #pragma unroll
    for (int off = 32; off >= 1; off >>= 1) m = fmaxf(m, __shfl_xor(m, off, 64));
    if ((t & 63) == 0) red[t >> 6] = m;
    __syncthreads();
    m = fmaxf(fmaxf(red[0], red[1]), fmaxf(red[2], red[3]));
    __syncthreads();
    float s = 0.f;
    #pragma unroll
    for (int j = 0; j < 8; ++j) { x[j] = __expf(x[j] - m); s += x[j]; }
    #pragma unroll
    for (int off = 32; off >= 1; off >>= 1) s += __shfl_xor(s, off, 64);
    if ((t & 63) == 0) red[t >> 6] = s;
    __syncthreads();
    s = red[0] + red[1] + red[2] + red[3];
    const float inv = 1.0f / s;
    bf16x8 o8;
    #pragma unroll
    for (int j = 0; j < 8; ++j) o8[j] = bfbits(x[j] * inv);
    *(bf16x8*)(p + t * 8) = o8;
}

// ---------------------------------------------------------------------------
extern "C" void kernel_launch(void* const* d_in, const int* in_sizes, int n_in,
                              void* d_out, int out_size, void* d_ws, size_t ws_size,
                              hipStream_t stream) {
    (void)in_sizes; (void)n_in; (void)out_size; (void)ws_size;
    const float* text = (const float*)d_in[0];
    const float* adj  = (const float*)d_in[1];
    const float* Wq   = (const float*)d_in[2];
    const float* bq   = (const float*)d_in[3];
    const float* Wk   = (const float*)d_in[4];
    const float* bk   = (const float*)d_in[5];
    const float* Wv   = (const float*)d_in[6];
    const float* bv   = (const float*)d_in[7];

    float* out0 = (float*)d_out;                 // output [B,N,D]
    float* out1 = out0 + (size_t)BATCH * ND;     // new_adj [B,N,N]

    bf16* w = (bf16*)d_ws;
    bf16* adjT = w;  w += BATCH * NN;
    bf16* qb   = w;  w += BATCH * ND;
    bf16* kb   = w;  w += BATCH * ND;
    bf16* vTb  = w;  w += BATCH * ND;   // [B][D][N]
    bf16* attn = w;  w += BATCH * NN;   // scores, then softmax in place
    bf16* nadj = w;  w += BATCH * NN;

    // textb + WT alias the head of nadj (dead until the attn@adj GEMM)
    bf16* textb = nadj;                     // [16384][256] bf16 = 8.4 MB
    bf16* WqT = nadj + BATCH * ND;          // 3 x [256][256] bf16
    bf16* WkT = WqT + DIM * DIM;
    bf16* WvT = WkT + DIM * DIM;

    transpose_adj_kernel<<<dim3(32, 32, BATCH), 256, 0, stream>>>(adj, adjT);
    cast_text<<<dim3(BATCH * SEQ * DIM / 2048), 256, 0, stream>>>(text, textb);
    prep_w<<<dim3(4, 4, 3), 256, 0, stream>>>(Wq, Wk, Wv, WqT, WkT, WvT);
    // q/k row-major bf16, v transposed -> vT[b][o][n]; bias fused
    qkv256<<<dim3(64, 1, 3), 512, 0, stream>>>(
        textb, WqT, WkT, WvT, bq, bk, bv, qb, kb, vTb);
    // scores = (q @ k^T) / 16  -> bf16
    gemm256<<<dim3(SEQ / 256, SEQ / 256, BATCH), 512, 0, stream>>>(
        qb, kb, nullptr, attn, SEQ, SEQ, DIM,
        (long long)ND, (long long)ND, 0, (long long)NN, 1.0f / 16.0f);
    softmax_rows<<<dim3(BATCH * SEQ), 256, 0, stream>>>(attn);
    // new_adj = attn @ adj  -> fp32 (d_out) + bf16 (ws)
    gemm256<<<dim3(SEQ / 256, SEQ / 256, BATCH), 512, 0, stream>>>(
        attn, adjT, out1, nadj, SEQ, SEQ, SEQ,
        (long long)NN, (long long)NN, (long long)NN, (long long)NN, 1.0f);
    // output = new_adj @ v  -> fp32 (d_out); 128x128 tile => 256 blocks
    gemm_bt<128, 128, 2, 2><<<dim3(16, 2, BATCH), 256, 0, stream>>>(
        nadj, vTb, out0, nullptr, SEQ, DIM, SEQ,
        (long long)NN, (long long)ND, (long long)ND, 0, 1.0f);
}

// Round 7
// 522.792 us; speedup vs baseline: 1.0408x; 1.0353x over previous
//
#include <hip/hip_runtime.h>
#include <hip/hip_bf16.h>
#include <cstdint>

#define BATCH 8
#define SEQ   2048
#define DIM   256
#define NN    ((size_t)SEQ * SEQ)   // 4194304 per batch
#define ND    ((size_t)SEQ * DIM)   // 524288 per batch

typedef __hip_bfloat16 bf16;
typedef __attribute__((ext_vector_type(8))) short bf16x8;
typedef __attribute__((ext_vector_type(4))) short bf16x4;
typedef __attribute__((ext_vector_type(4))) float f32x4;

__device__ __forceinline__ short bfbits(float f) {
    bf16 b = __float2bfloat16(f);
    return *reinterpret_cast<short*>(&b);
}
__device__ __forceinline__ float bf2f(short s) {
    bf16 b = *reinterpret_cast<bf16*>(&s);
    return __bfloat162float(b);
}

// async global->LDS, 16B per lane; LDS dest = wave-uniform base + lane*16
__device__ __forceinline__ void async16(const void* g, void* l) {
    __builtin_amdgcn_global_load_lds(
        (__attribute__((address_space(1))) unsigned int*)(uintptr_t)g,
        (__attribute__((address_space(3))) unsigned int*)(uintptr_t)l,
        16, 0, 0);
}

// ---------------------------------------------------------------------------
// Fused prep: one launch, block-range dispatch (branch is block-uniform).
//   blocks [0, 8192)        : adj [B][N][N] f32 -> adjT bf16 (64x64 tiles)
//   blocks [8192, 10240)    : text fp32 -> bf16 flat cast
//   blocks [10240, 10288)   : W fp32 [in][out] -> WT bf16 [out][in]
// ---------------------------------------------------------------------------
__global__ __launch_bounds__(256) void prep_all(
        const float* __restrict__ adj,  bf16* __restrict__ adjT,
        const float* __restrict__ text, bf16* __restrict__ textb,
        const float* __restrict__ Wq, const float* __restrict__ Wk,
        const float* __restrict__ Wv,
        bf16* __restrict__ WqT, bf16* __restrict__ WkT, bf16* __restrict__ WvT) {
    __shared__ float tile[64][67];
    const int bid = blockIdx.x;
    const int tid = threadIdx.x;

    if (bid < 8192) {                       // ---- transpose adj ----
        const int b   = bid >> 10;
        const int rem = bid & 1023;
        const int i0  = (rem >> 5) << 6;
        const int j0  = (rem & 31) << 6;
        const float* src = adj + (size_t)b * NN;
        bf16* dst = adjT + (size_t)b * NN;
        const int r  = tid >> 4;
        const int c4 = (tid & 15) << 2;
        #pragma unroll
        for (int p = 0; p < 4; ++p) {
            const int row = r + p * 16;
            const float4 v = *(const float4*)(src + (size_t)(i0 + row) * SEQ + j0 + c4);
            tile[row][c4 + 0] = v.x;
            tile[row][c4 + 1] = v.y;
            tile[row][c4 + 2] = v.z;
            tile[row][c4 + 3] = v.w;
        }
        __syncthreads();
        #pragma unroll
        for (int p = 0; p < 4; ++p) {
            const int jj = r + p * 16;
            bf16x4 o;
            o[0] = bfbits(tile[c4 + 0][jj]);
            o[1] = bfbits(tile[c4 + 1][jj]);
            o[2] = bfbits(tile[c4 + 2][jj]);
            o[3] = bfbits(tile[c4 + 3][jj]);
            *(bf16x4*)(dst + (size_t)(j0 + jj) * SEQ + i0 + c4) = o;
        }
    } else if (bid < 10240) {               // ---- cast text ----
        const size_t i = ((size_t)(bid - 8192) * 256 + tid) * 8;
        const float4 a = *(const float4*)(text + i);
        const float4 b = *(const float4*)(text + i + 4);
        bf16x8 o;
        o[0] = bfbits(a.x); o[1] = bfbits(a.y); o[2] = bfbits(a.z); o[3] = bfbits(a.w);
        o[4] = bfbits(b.x); o[5] = bfbits(b.y); o[6] = bfbits(b.z); o[7] = bfbits(b.w);
        *(bf16x8*)(textb + i) = o;
    } else {                                // ---- transpose+cast weights ----
        const int q  = bid - 10240;         // 0..47
        const int z  = q >> 4;              // 0..2
        const int rm = q & 15;
        const float* src = (z == 0) ? Wq : (z == 1) ? Wk : Wv;
        bf16* dst = (z == 0) ? WqT : (z == 1) ? WkT : WvT;
        const int i0 = (rm >> 2) << 6;
        const int j0 = (rm & 3) << 6;
        const int r  = tid >> 4;
        const int c4 = (tid & 15) << 2;
        #pragma unroll
        for (int p = 0; p < 4; ++p) {
            const int row = r + p * 16;
            const float4 v = *(const float4*)(src + (size_t)(i0 + row) * DIM + j0 + c4);
            tile[row][c4 + 0] = v.x;
            tile[row][c4 + 1] = v.y;
            tile[row][c4 + 2] = v.z;
            tile[row][c4 + 3] = v.w;
        }
        __syncthreads();
        #pragma unroll
        for (int p = 0; p < 4; ++p) {
            const int jj = r + p * 16;
            bf16x4 o;
            o[0] = bfbits(tile[c4 + 0][jj]);
            o[1] = bfbits(tile[c4 + 1][jj]);
            o[2] = bfbits(tile[c4 + 2][jj]);
            o[3] = bfbits(tile[c4 + 3][jj]);
            *(bf16x4*)(dst + (size_t)(j0 + jj) * DIM + i0 + c4) = o;
        }
    }
}

// ---------------------------------------------------------------------------
// 2-barrier 128-row GEMM (output GEMM new_adj @ v): 128x64 tile, 512 blocks
// = 2 blocks/CU (R6 showed 128x128 @ 1 block/CU was ~13us slower).
// ---------------------------------------------------------------------------
template <int BM, int BN, int WR, int WC>
__global__ __launch_bounds__(256) void gemm_bt(
        const bf16* __restrict__ A, const bf16* __restrict__ Bt,
        float* __restrict__ Cf, bf16* __restrict__ Cb,
        int M, int Ncols, int K,
        long long sA, long long sB, long long sCf, long long sCb,
        float scale) {
    constexpr int FI = BM / WR / 16;
    constexpr int FJ = BN / WC / 16;
    constexpr int CA = BM / 32;
    constexpr int CB = BN / 32;

    __shared__ bf16 As[BM * 64];
    __shared__ bf16 Bs[BN * 64];
    const int bz = blockIdx.z;
    const bf16* Ab = A  + (size_t)bz * sA;
    const bf16* Bb = Bt + (size_t)bz * sB;
    const int row0 = blockIdx.x * BM;
    const int col0 = blockIdx.y * BN;
    const int tid  = threadIdx.x;
    const int wave = tid >> 6;
    const int lane = tid & 63;
    const int wr0 = (wave / WC) * (BM / WR);
    const int wc0 = (wave % WC) * (BN / WC);
    const int fl = lane & 15;
    const int fq = lane >> 4;
    const int srow = tid >> 3;
    const int sk   = ((tid & 7) ^ (srow & 7)) * 8;

    f32x4 acc[FI][FJ] = {};

    for (int k0 = 0; k0 < K; k0 += 64) {
        #pragma unroll
        for (int a = 0; a < CA; ++a)
            async16(Ab + (size_t)(row0 + a * 32 + srow) * K + k0 + sk,
                    As + a * 2048 + tid * 8);
        #pragma unroll
        for (int a = 0; a < CB; ++a)
            async16(Bb + (size_t)(col0 + a * 32 + srow) * K + k0 + sk,
                    Bs + a * 2048 + tid * 8);
        __syncthreads();
        #pragma unroll
        for (int m = 0; m < 2; ++m) {
            const int p = ((m * 4 + fq) ^ (fl & 7)) * 8;
            bf16x8 af[FI], bg[FJ];
            #pragma unroll
            for (int i = 0; i < FI; ++i)
                af[i] = *(const bf16x8*)(As + (wr0 + i * 16 + fl) * 64 + p);
            #pragma unroll
            for (int j = 0; j < FJ; ++j)
                bg[j] = *(const bf16x8*)(Bs + (wc0 + j * 16 + fl) * 64 + p);
            #pragma unroll
            for (int i = 0; i < FI; ++i)
                #pragma unroll
                for (int j = 0; j < FJ; ++j)
                    acc[i][j] = __builtin_amdgcn_mfma_f32_16x16x32_bf16(
                        af[i], bg[j], acc[i][j], 0, 0, 0);
        }
        __syncthreads();
    }

    #pragma unroll
    for (int i = 0; i < FI; ++i) {
        #pragma unroll
        for (int j = 0; j < FJ; ++j) {
            #pragma unroll
            for (int r = 0; r < 4; ++r) {
                const int row = row0 + wr0 + i * 16 + fq * 4 + r;
                const int col = col0 + wc0 + j * 16 + fl;
                const float val = acc[i][j][r] * scale;
                if (Cf) Cf[(size_t)bz * sCf + (size_t)row * Ncols + col] = val;
                if (Cb) Cb[(size_t)bz * sCb + (size_t)row * Ncols + col] =
                    __float2bfloat16(val);
            }
        }
    }
}

// ---------------------------------------------------------------------------
// 256x256-tile 8-wave 8-phase GEMM body (PINNED round-3 schedule, 155us on
// the K=2048 dispatch): C = scale*(A @ Bt^T)+bias.
// Staging SPREAD one call per phase (burst-issue at ph4/8 measured -12% in
// round 5 -- do not cluster). Counted vmcnt(4) at phases 4/8 only.
// ---------------------------------------------------------------------------
__device__ __forceinline__ void gemm256_body(
        const bf16* __restrict__ Ab, const bf16* __restrict__ Bb,
        float* __restrict__ Cf, bf16* __restrict__ Cb,
        int Ncols, int K, int row0, int col0, float scale,
        const float* __restrict__ bias, int transC) {
    __shared__ bf16 As[2][2][8192];   // [buf][half][128*64]
    __shared__ bf16 Bs[2][2][8192];

    const int tid  = threadIdx.x;
    const int wave = tid >> 6;
    const int lane = tid & 63;
    const int wm = wave >> 2;         // 0..1 -> A half / 128-row block
    const int wn = wave & 3;          // 0..3 -> 64-col block
    const int fl = lane & 15;
    const int fq = lane >> 4;

    const int NT = K >> 6;            // K-tiles of 64 (even, >=2)

    int aoff[2], boff[2];
    #pragma unroll
    for (int m = 0; m < 2; ++m) {
        const int c = ((m * 4 + fq) ^ (fl & 7)) * 8;
        aoff[m] = fl * 64 + c;
        boff[m] = ((wn & 1) * 64 + fl) * 64 + c;
    }

    auto stageA = [&](int buf, int h, int tt) {
        const bf16* g = Ab + (size_t)(row0 + h * 128) * K + tt * 64;
        #pragma unroll
        for (int q = 0; q < 2; ++q) {
            const int idx = q * 512 + tid;
            const int r = idx >> 3;
            const int gk = ((idx & 7) ^ (r & 7)) * 8;
            async16(g + (size_t)r * K + gk, &As[buf][h][idx * 8]);
        }
    };
    auto stageB = [&](int buf, int h, int tt) {
        const bf16* g = Bb + (size_t)(col0 + h * 128) * K + tt * 64;
        #pragma unroll
        for (int q = 0; q < 2; ++q) {
            const int idx = q * 512 + tid;
            const int r = idx >> 3;
            const int gk = ((idx & 7) ^ (r & 7)) * 8;
            async16(g + (size_t)r * K + gk, &Bs[buf][h][idx * 8]);
        }
    };

    f32x4 acc[8][4] = {};
    bf16x8 af[4][2], b01[2][2], b23[2][2];

#define LOADA(buf, ib) do {                                                   \
    const bf16* _s = &As[buf][wm][0];                                         \
    _Pragma("unroll") for (int i = 0; i < 4; ++i)                             \
      _Pragma("unroll") for (int m = 0; m < 2; ++m)                           \
        af[i][m] = *(const bf16x8*)(_s + ((ib) + i) * 1024 + aoff[m]);        \
} while (0)
#define LOADB(buf, dst, jb) do {                                              \
    const bf16* _s = &Bs[buf][wn >> 1][0];                                    \
    _Pragma("unroll") for (int j = 0; j < 2; ++j)                             \
      _Pragma("unroll") for (int m = 0; m < 2; ++m)                           \
        dst[j][m] = *(const bf16x8*)(_s + ((jb) + j) * 1024 + boff[m]);       \
} while (0)
#define MFMA_Q(IB, BB, JB) do {                                               \
    __builtin_amdgcn_s_setprio(1);                                            \
    _Pragma("unroll") for (int m = 0; m < 2; ++m)                             \
      _Pragma("unroll") for (int i = 0; i < 4; ++i)                           \
        _Pragma("unroll") for (int j = 0; j < 2; ++j)                         \
            acc[(IB) + i][(JB) + j] = __builtin_amdgcn_mfma_f32_16x16x32_bf16(\
                af[i][m], BB[j][m], acc[(IB) + i][(JB) + j], 0, 0, 0);        \
    __builtin_amdgcn_s_setprio(0);                                            \
} while (0)
#define SBAR  __builtin_amdgcn_s_barrier()
#define LGKM0 asm volatile("s_waitcnt lgkmcnt(0)" ::: "memory")
#define VM4   asm volatile("s_waitcnt vmcnt(4)" ::: "memory")

    // prologue: buf0 <- t0 (all 4 halves), buf1 <- t1 B halves.
    stageA(0, 0, 0); stageA(0, 1, 0); stageB(0, 0, 0); stageB(0, 1, 0);
    stageB(1, 0, 1); stageB(1, 1, 1);
    VM4;            // t0 fully landed; t1's B pair (4 loads) stays in flight
    SBAR;

    for (int t = 0; t < NT; t += 2) {
        const int t2 = (t + 2 < NT) ? t + 2 : NT - 1;   // clamped prefetch
        const int t3 = (t + 3 < NT) ? t + 3 : NT - 1;
        // ---- K-tile t (buf0) ----
        LOADA(0, 0); LOADB(0, b01, 0);
        stageA(1, 0, t + 1);
        SBAR; LGKM0; MFMA_Q(0, b01, 0); SBAR;
        LOADB(0, b23, 2);
        stageA(1, 1, t + 1);
        SBAR; LGKM0; MFMA_Q(0, b23, 2); SBAR;
        LOADA(0, 4);
        stageB(0, 0, t2);
        SBAR; LGKM0; MFMA_Q(4, b23, 2); SBAR;
        stageB(0, 1, t2);
        SBAR; MFMA_Q(4, b01, 0);
        VM4;        // completes t1's 4 half-tiles; t2 B pair stays in flight
        SBAR;
        // ---- K-tile t+1 (buf1) ----
        LOADA(1, 0); LOADB(1, b01, 0);
        stageA(0, 0, t2);
        SBAR; LGKM0; MFMA_Q(0, b01, 0); SBAR;
        LOADB(1, b23, 2);
        stageA(0, 1, t2);
        SBAR; LGKM0; MFMA_Q(0, b23, 2); SBAR;
        LOADA(1, 4);
        stageB(1, 0, t3);
        SBAR; LGKM0; MFMA_Q(4, b23, 2); SBAR;
        stageB(1, 1, t3);
        SBAR; MFMA_Q(4, b01, 0);
        VM4;        // completes t2's 4 half-tiles; t3 B pair stays in flight
        SBAR;
    }

    // drain tail prefetches before epilogue / endpgm
    asm volatile("s_waitcnt vmcnt(0)" ::: "memory");
    SBAR;

#undef LOADA
#undef LOADB
#undef MFMA_Q
#undef SBAR
#undef LGKM0
#undef VM4

    // C/D layout: col = lane&15, row = (lane>>4)*4 + reg
    #pragma unroll
    for (int i = 0; i < 8; ++i) {
        #pragma unroll
        for (int j = 0; j < 4; ++j) {
            const int rowb = row0 + wm * 128 + i * 16 + fq * 4;
            const int col  = col0 + wn * 64 + j * 16 + fl;
            const float badd = bias ? bias[col] : 0.0f;
            if (transC) {
                // vT[b][o][n] = [8][256][2048]; rowb..rowb+3 within one batch
                bf16x4 o;
                #pragma unroll
                for (int r = 0; r < 4; ++r)
                    o[r] = bfbits(acc[i][j][r] * scale + badd);
                *(bf16x4*)(Cb + (size_t)(rowb >> 11) * ND +
                           (size_t)col * SEQ + (rowb & 2047)) = o;
            } else {
                #pragma unroll
                for (int r = 0; r < 4; ++r) {
                    const int row = rowb + r;
                    const float val = acc[i][j][r] * scale + badd;
                    if (Cf) Cf[(size_t)row * Ncols + col] = val;
                    if (Cb) Cb[(size_t)row * Ncols + col] = __float2bfloat16(val);
                }
            }
        }
    }
}

// ---------------------------------------------------------------------------
// batched square-GEMM wrapper with XCD-bijective tile swizzle
// ---------------------------------------------------------------------------
__global__ __launch_bounds__(512, 2) void gemm256(
        const bf16* __restrict__ A, const bf16* __restrict__ Bt,
        float* __restrict__ Cf, bf16* __restrict__ Cb,
        int M, int Ncols, int K,
        long long sA, long long sB, long long sCf, long long sCb,
        float scale) {
    (void)M;
    const int bz = blockIdx.z;
    const int gx = gridDim.x, gy = gridDim.y;
    const int nwg = gx * gy;
    int lwg = blockIdx.x + blockIdx.y * gx;
    int swz = lwg;
    if ((nwg & 7) == 0) swz = (lwg & 7) * (nwg >> 3) + (lwg >> 3);
    const int row0 = (swz % gx) * 256;
    const int col0 = (swz / gx) * 256;
    gemm256_body(A + (size_t)bz * sA, Bt + (size_t)bz * sB,
                 Cf ? Cf + (size_t)bz * sCf : nullptr,
                 Cb ? Cb + (size_t)bz * sCb : nullptr,
                 Ncols, K, row0, col0, scale, nullptr, 0);
}

// ---------------------------------------------------------------------------
// fused QKV projection: z selects {Wq,Wk,Wv}; v written transposed to vT.
// A = textb [16384][256] bf16; WT = [256 out][256 in] bf16.
// ---------------------------------------------------------------------------
__global__ __launch_bounds__(512, 2) void qkv256(
        const bf16* __restrict__ textb,
        const bf16* __restrict__ WqT, const bf16* __restrict__ WkT,
        const bf16* __restrict__ WvT,
        const float* __restrict__ bq, const float* __restrict__ bk,
        const float* __restrict__ bv,
        bf16* __restrict__ q, bf16* __restrict__ k, bf16* __restrict__ vT) {
    const int x = blockIdx.x;                       // 0..63
    const int swz = (x & 7) * 8 + (x >> 3);         // XCD swizzle (64 wgs)
    const int row0 = swz * 256;
    const int z = blockIdx.z;
    const bf16* W = (z == 0) ? WqT : (z == 1) ? WkT : WvT;
    const float* bias = (z == 0) ? bq : (z == 1) ? bk : bv;
    bf16* out = (z == 0) ? q : (z == 1) ? k : vT;
    gemm256_body(textb, W, nullptr, out, DIM, DIM, row0, 0, 1.0f,
                 bias, (z == 2) ? 1 : 0);
}

// ---------------------------------------------------------------------------
// in-place row softmax: ONE WAVE PER ROW (no LDS, no barriers).
// 4 waves/block, grid = rows/4. Lane holds 32 elems as 4 x bf16x8 at
// [j*512 + lane*8] -> each load/store instr covers a contiguous 1KiB.
// ---------------------------------------------------------------------------
__global__ __launch_bounds__(256) void softmax_rows(bf16* __restrict__ S) {
    const int w    = threadIdx.x >> 6;
    const int lane = threadIdx.x & 63;
    bf16* p = S + ((size_t)blockIdx.x * 4 + w) * SEQ;
    bf16x8 v[4];
    float x[32];
    #pragma unroll
    for (int j = 0; j < 4; ++j) {
        v[j] = *(const bf16x8*)(p + j * 512 + lane * 8);
        #pragma unroll
        for (int e = 0; e < 8; ++e) x[j * 8 + e] = bf2f(v[j][e]);
    }
    float m = x[0];
    #pragma unroll
    for (int i = 1; i < 32; ++i) m = fmaxf(m, x[i]);
    #pragma unroll
    for (int off = 32; off >= 1; off >>= 1) m = fmaxf(m, __shfl_xor(m, off, 64));
    float s = 0.f;
    #pragma unroll
    for (int i = 0; i < 32; ++i) { x[i] = __expf(x[i] - m); s += x[i]; }
    #pragma unroll
    for (int off = 32; off >= 1; off >>= 1) s += __shfl_xor(s, off, 64);
    const float inv = 1.0f / s;
    #pragma unroll
    for (int j = 0; j < 4; ++j) {
        bf16x8 o;
        #pragma unroll
        for (int e = 0; e < 8; ++e) o[e] = bfbits(x[j * 8 + e] * inv);
        *(bf16x8*)(p + j * 512 + lane * 8) = o;
    }
}

// ---------------------------------------------------------------------------
extern "C" void kernel_launch(void* const* d_in, const int* in_sizes, int n_in,
                              void* d_out, int out_size, void* d_ws, size_t ws_size,
                              hipStream_t stream) {
    (void)in_sizes; (void)n_in; (void)out_size; (void)ws_size;
    const float* text = (const float*)d_in[0];
    const float* adj  = (const float*)d_in[1];
    const float* Wq   = (const float*)d_in[2];
    const float* bq   = (const float*)d_in[3];
    const float* Wk   = (const float*)d_in[4];
    const float* bk   = (const float*)d_in[5];
    const float* Wv   = (const float*)d_in[6];
    const float* bv   = (const float*)d_in[7];

    float* out0 = (float*)d_out;                 // output [B,N,D]
    float* out1 = out0 + (size_t)BATCH * ND;     // new_adj [B,N,N]

    bf16* w = (bf16*)d_ws;
    bf16* adjT = w;  w += BATCH * NN;
    bf16* qb   = w;  w += BATCH * ND;
    bf16* kb   = w;  w += BATCH * ND;
    bf16* vTb  = w;  w += BATCH * ND;   // [B][D][N]
    bf16* attn = w;  w += BATCH * NN;   // scores, then softmax in place
    bf16* nadj = w;  w += BATCH * NN;

    // textb + WT alias the head of nadj (dead until the attn@adj GEMM)
    bf16* textb = nadj;                     // [16384][256] bf16 = 8.4 MB
    bf16* WqT = nadj + BATCH * ND;          // 3 x [256][256] bf16
    bf16* WkT = WqT + DIM * DIM;
    bf16* WvT = WkT + DIM * DIM;

    // fused prep: transpose adj (8192 blocks) + cast text (2048) + W^T (48)
    prep_all<<<dim3(10288), 256, 0, stream>>>(
        adj, adjT, text, textb, Wq, Wk, Wv, WqT, WkT, WvT);
    // q/k row-major bf16, v transposed -> vT[b][o][n]; bias fused
    qkv256<<<dim3(64, 1, 3), 512, 0, stream>>>(
        textb, WqT, WkT, WvT, bq, bk, bv, qb, kb, vTb);
    // scores = (q @ k^T) / 16  -> bf16
    gemm256<<<dim3(SEQ / 256, SEQ / 256, BATCH), 512, 0, stream>>>(
        qb, kb, nullptr, attn, SEQ, SEQ, DIM,
        (long long)ND, (long long)ND, 0, (long long)NN, 1.0f / 16.0f);
    softmax_rows<<<dim3(BATCH * SEQ / 4), 256, 0, stream>>>(attn);
    // new_adj = attn @ adj  -> fp32 (d_out) + bf16 (ws)
    gemm256<<<dim3(SEQ / 256, SEQ / 256, BATCH), 512, 0, stream>>>(
        attn, adjT, out1, nadj, SEQ, SEQ, SEQ,
        (long long)NN, (long long)NN, (long long)NN, (long long)NN, 1.0f);
    // output = new_adj @ v  -> fp32 (d_out); 128x64 tile => 512 blocks
    gemm_bt<128, 64, 4, 1><<<dim3(16, 4, BATCH), 256, 0, stream>>>(
        nadj, vTb, out0, nullptr, SEQ, DIM, SEQ,
        (long long)NN, (long long)ND, (long long)ND, 0, 1.0f);
}

// Round 9
// 520.487 us; speedup vs baseline: 1.0454x; 1.0044x over previous
//
#include <hip/hip_runtime.h>
#include <hip/hip_bf16.h>
#include <cstdint>

#define BATCH 8
#define SEQ   2048
#define DIM   256
#define NN    ((size_t)SEQ * SEQ)   // 4194304 per batch
#define ND    ((size_t)SEQ * DIM)   // 524288 per batch

typedef __hip_bfloat16 bf16;
typedef __attribute__((ext_vector_type(8))) short bf16x8;
typedef __attribute__((ext_vector_type(4))) short bf16x4;
typedef __attribute__((ext_vector_type(4))) float f32x4;

__device__ __forceinline__ short bfbits(float f) {
    bf16 b = __float2bfloat16(f);
    return *reinterpret_cast<short*>(&b);
}
__device__ __forceinline__ float bf2f(short s) {
    bf16 b = *reinterpret_cast<bf16*>(&s);
    return __bfloat162float(b);
}

// async global->LDS, 16B per lane; LDS dest = wave-uniform base + lane*16
__device__ __forceinline__ void async16(const void* g, void* l) {
    __builtin_amdgcn_global_load_lds(
        (__attribute__((address_space(1))) unsigned int*)(uintptr_t)g,
        (__attribute__((address_space(3))) unsigned int*)(uintptr_t)l,
        16, 0, 0);
}

// ---------------------------------------------------------------------------
// Fused prep: one launch, block-range dispatch (branch is block-uniform).
//   blocks [0, 8192)        : adj [B][N][N] f32 -> adjT bf16 (64x64 tiles)
//   blocks [8192, 10240)    : text fp32 -> bf16 flat cast
//   blocks [10240, 10288)   : W fp32 [in][out] -> WT bf16 [out][in]
// ---------------------------------------------------------------------------
__global__ __launch_bounds__(256) void prep_all(
        const float* __restrict__ adj,  bf16* __restrict__ adjT,
        const float* __restrict__ text, bf16* __restrict__ textb,
        const float* __restrict__ Wq, const float* __restrict__ Wk,
        const float* __restrict__ Wv,
        bf16* __restrict__ WqT, bf16* __restrict__ WkT, bf16* __restrict__ WvT) {
    __shared__ float tile[64][67];
    const int bid = blockIdx.x;
    const int tid = threadIdx.x;

    if (bid < 8192) {                       // ---- transpose adj ----
        const int b   = bid >> 10;
        const int rem = bid & 1023;
        const int i0  = (rem >> 5) << 6;
        const int j0  = (rem & 31) << 6;
        const float* src = adj + (size_t)b * NN;
        bf16* dst = adjT + (size_t)b * NN;
        const int r  = tid >> 4;
        const int c4 = (tid & 15) << 2;
        #pragma unroll
        for (int p = 0; p < 4; ++p) {
            const int row = r + p * 16;
            const float4 v = *(const float4*)(src + (size_t)(i0 + row) * SEQ + j0 + c4);
            tile[row][c4 + 0] = v.x;
            tile[row][c4 + 1] = v.y;
            tile[row][c4 + 2] = v.z;
            tile[row][c4 + 3] = v.w;
        }
        __syncthreads();
        #pragma unroll
        for (int p = 0; p < 4; ++p) {
            const int jj = r + p * 16;
            bf16x4 o;
            o[0] = bfbits(tile[c4 + 0][jj]);
            o[1] = bfbits(tile[c4 + 1][jj]);
            o[2] = bfbits(tile[c4 + 2][jj]);
            o[3] = bfbits(tile[c4 + 3][jj]);
            *(bf16x4*)(dst + (size_t)(j0 + jj) * SEQ + i0 + c4) = o;
        }
    } else if (bid < 10240) {               // ---- cast text ----
        const size_t i = ((size_t)(bid - 8192) * 256 + tid) * 8;
        const float4 a = *(const float4*)(text + i);
        const float4 b = *(const float4*)(text + i + 4);
        bf16x8 o;
        o[0] = bfbits(a.x); o[1] = bfbits(a.y); o[2] = bfbits(a.z); o[3] = bfbits(a.w);
        o[4] = bfbits(b.x); o[5] = bfbits(b.y); o[6] = bfbits(b.z); o[7] = bfbits(b.w);
        *(bf16x8*)(textb + i) = o;
    } else {                                // ---- transpose+cast weights ----
        const int q  = bid - 10240;         // 0..47
        const int z  = q >> 4;              // 0..2
        const int rm = q & 15;
        const float* src = (z == 0) ? Wq : (z == 1) ? Wk : Wv;
        bf16* dst = (z == 0) ? WqT : (z == 1) ? WkT : WvT;
        const int i0 = (rm >> 2) << 6;
        const int j0 = (rm & 3) << 6;
        const int r  = tid >> 4;
        const int c4 = (tid & 15) << 2;
        #pragma unroll
        for (int p = 0; p < 4; ++p) {
            const int row = r + p * 16;
            const float4 v = *(const float4*)(src + (size_t)(i0 + row) * DIM + j0 + c4);
            tile[row][c4 + 0] = v.x;
            tile[row][c4 + 1] = v.y;
            tile[row][c4 + 2] = v.z;
            tile[row][c4 + 3] = v.w;
        }
        __syncthreads();
        #pragma unroll
        for (int p = 0; p < 4; ++p) {
            const int jj = r + p * 16;
            bf16x4 o;
            o[0] = bfbits(tile[c4 + 0][jj]);
            o[1] = bfbits(tile[c4 + 1][jj]);
            o[2] = bfbits(tile[c4 + 2][jj]);
            o[3] = bfbits(tile[c4 + 3][jj]);
            *(bf16x4*)(dst + (size_t)(j0 + jj) * DIM + i0 + c4) = o;
        }
    }
}

// ---------------------------------------------------------------------------
// 2-barrier 128-row GEMM (output GEMM new_adj @ v): 128x64 tile, 512 blocks.
// ---------------------------------------------------------------------------
template <int BM, int BN, int WR, int WC>
__global__ __launch_bounds__(256) void gemm_bt(
        const bf16* __restrict__ A, const bf16* __restrict__ Bt,
        float* __restrict__ Cf, bf16* __restrict__ Cb,
        int M, int Ncols, int K,
        long long sA, long long sB, long long sCf, long long sCb,
        float scale) {
    constexpr int FI = BM / WR / 16;
    constexpr int FJ = BN / WC / 16;
    constexpr int CA = BM / 32;
    constexpr int CB = BN / 32;

    __shared__ bf16 As[BM * 64];
    __shared__ bf16 Bs[BN * 64];
    const int bz = blockIdx.z;
    const bf16* Ab = A  + (size_t)bz * sA;
    const bf16* Bb = Bt + (size_t)bz * sB;
    const int row0 = blockIdx.x * BM;
    const int col0 = blockIdx.y * BN;
    const int tid  = threadIdx.x;
    const int wave = tid >> 6;
    const int lane = tid & 63;
    const int wr0 = (wave / WC) * (BM / WR);
    const int wc0 = (wave % WC) * (BN / WC);
    const int fl = lane & 15;
    const int fq = lane >> 4;
    const int srow = tid >> 3;
    const int sk   = ((tid & 7) ^ (srow & 7)) * 8;

    f32x4 acc[FI][FJ] = {};

    for (int k0 = 0; k0 < K; k0 += 64) {
        #pragma unroll
        for (int a = 0; a < CA; ++a)
            async16(Ab + (size_t)(row0 + a * 32 + srow) * K + k0 + sk,
                    As + a * 2048 + tid * 8);
        #pragma unroll
        for (int a = 0; a < CB; ++a)
            async16(Bb + (size_t)(col0 + a * 32 + srow) * K + k0 + sk,
                    Bs + a * 2048 + tid * 8);
        __syncthreads();
        #pragma unroll
        for (int m = 0; m < 2; ++m) {
            const int p = ((m * 4 + fq) ^ (fl & 7)) * 8;
            bf16x8 af[FI], bg[FJ];
            #pragma unroll
            for (int i = 0; i < FI; ++i)
                af[i] = *(const bf16x8*)(As + (wr0 + i * 16 + fl) * 64 + p);
            #pragma unroll
            for (int j = 0; j < FJ; ++j)
                bg[j] = *(const bf16x8*)(Bs + (wc0 + j * 16 + fl) * 64 + p);
            #pragma unroll
            for (int i = 0; i < FI; ++i)
                #pragma unroll
                for (int j = 0; j < FJ; ++j)
                    acc[i][j] = __builtin_amdgcn_mfma_f32_16x16x32_bf16(
                        af[i], bg[j], acc[i][j], 0, 0, 0);
        }
        __syncthreads();
    }

    #pragma unroll
    for (int i = 0; i < FI; ++i) {
        #pragma unroll
        for (int j = 0; j < FJ; ++j) {
            #pragma unroll
            for (int r = 0; r < 4; ++r) {
                const int row = row0 + wr0 + i * 16 + fq * 4 + r;
                const int col = col0 + wc0 + j * 16 + fl;
                const float val = acc[i][j][r] * scale;
                if (Cf) Cf[(size_t)bz * sCf + (size_t)row * Ncols + col] = val;
                if (Cb) Cb[(size_t)bz * sCb + (size_t)row * Ncols + col] =
                    __float2bfloat16(val);
            }
        }
    }
}

// ---------------------------------------------------------------------------
// 256x256-tile 8-wave 8-phase GEMM body (PINNED round-3 schedule):
// Staging spread one call per phase; counted vmcnt(4) at phases 4/8 only.
// ---------------------------------------------------------------------------
__device__ __forceinline__ void gemm256_body(
        const bf16* __restrict__ Ab, const bf16* __restrict__ Bb,
        float* __restrict__ Cf, bf16* __restrict__ Cb,
        int Ncols, int K, int row0, int col0, float scale,
        const float* __restrict__ bias, int transC) {
    __shared__ bf16 As[2][2][8192];   // [buf][half][128*64]
    __shared__ bf16 Bs[2][2][8192];

    const int tid  = threadIdx.x;
    const int wave = tid >> 6;
    const int lane = tid & 63;
    const int wm = wave >> 2;         // 0..1 -> A half / 128-row block
    const int wn = wave & 3;          // 0..3 -> 64-col block
    const int fl = lane & 15;
    const int fq = lane >> 4;

    const int NT = K >> 6;            // K-tiles of 64 (even, >=2)

    int aoff[2], boff[2];
    #pragma unroll
    for (int m = 0; m < 2; ++m) {
        const int c = ((m * 4 + fq) ^ (fl & 7)) * 8;
        aoff[m] = fl * 64 + c;
        boff[m] = ((wn & 1) * 64 + fl) * 64 + c;
    }

    auto stageA = [&](int buf, int h, int tt) {
        const bf16* g = Ab + (size_t)(row0 + h * 128) * K + tt * 64;
        #pragma unroll
        for (int q = 0; q < 2; ++q) {
            const int idx = q * 512 + tid;
            const int r = idx >> 3;
            const int gk = ((idx & 7) ^ (r & 7)) * 8;
            async16(g + (size_t)r * K + gk, &As[buf][h][idx * 8]);
        }
    };
    auto stageB = [&](int buf, int h, int tt) {
        const bf16* g = Bb + (size_t)(col0 + h * 128) * K + tt * 64;
        #pragma unroll
        for (int q = 0; q < 2; ++q) {
            const int idx = q * 512 + tid;
            const int r = idx >> 3;
            const int gk = ((idx & 7) ^ (r & 7)) * 8;
            async16(g + (size_t)r * K + gk, &Bs[buf][h][idx * 8]);
        }
    };

    f32x4 acc[8][4] = {};
    bf16x8 af[4][2], b01[2][2], b23[2][2];

#define LOADA(buf, ib) do {                                                   \
    const bf16* _s = &As[buf][wm][0];                                         \
    _Pragma("unroll") for (int i = 0; i < 4; ++i)                             \
      _Pragma("unroll") for (int m = 0; m < 2; ++m)                           \
        af[i][m] = *(const bf16x8*)(_s + ((ib) + i) * 1024 + aoff[m]);        \
} while (0)
#define LOADB(buf, dst, jb) do {                                              \
    const bf16* _s = &Bs[buf][wn >> 1][0];                                    \
    _Pragma("unroll") for (int j = 0; j < 2; ++j)                             \
      _Pragma("unroll") for (int m = 0; m < 2; ++m)                           \
        dst[j][m] = *(const bf16x8*)(_s + ((jb) + j) * 1024 + boff[m]);       \
} while (0)
#define MFMA_Q(IB, BB, JB) do {                                               \
    __builtin_amdgcn_s_setprio(1);                                            \
    _Pragma("unroll") for (int m = 0; m < 2; ++m)                             \
      _Pragma("unroll") for (int i = 0; i < 4; ++i)                           \
        _Pragma("unroll") for (int j = 0; j < 2; ++j)                         \
            acc[(IB) + i][(JB) + j] = __builtin_amdgcn_mfma_f32_16x16x32_bf16(\
                af[i][m], BB[j][m], acc[(IB) + i][(JB) + j], 0, 0, 0);        \
    __builtin_amdgcn_s_setprio(0);                                            \
} while (0)
#define SBAR  __builtin_amdgcn_s_barrier()
#define LGKM0 asm volatile("s_waitcnt lgkmcnt(0)" ::: "memory")
#define VM4   asm volatile("s_waitcnt vmcnt(4)" ::: "memory")

    // prologue: buf0 <- t0 (all 4 halves), buf1 <- t1 B halves.
    stageA(0, 0, 0); stageA(0, 1, 0); stageB(0, 0, 0); stageB(0, 1, 0);
    stageB(1, 0, 1); stageB(1, 1, 1);
    VM4;            // t0 fully landed; t1's B pair (4 loads) stays in flight
    SBAR;

    for (int t = 0; t < NT; t += 2) {
        const int t2 = (t + 2 < NT) ? t + 2 : NT - 1;   // clamped prefetch
        const int t3 = (t + 3 < NT) ? t + 3 : NT - 1;
        // ---- K-tile t (buf0) ----
        LOADA(0, 0); LOADB(0, b01, 0);
        stageA(1, 0, t + 1);
        SBAR; LGKM0; MFMA_Q(0, b01, 0); SBAR;
        LOADB(0, b23, 2);
        stageA(1, 1, t + 1);
        SBAR; LGKM0; MFMA_Q(0, b23, 2); SBAR;
        LOADA(0, 4);
        stageB(0, 0, t2);
        SBAR; LGKM0; MFMA_Q(4, b23, 2); SBAR;
        stageB(0, 1, t2);
        SBAR; MFMA_Q(4, b01, 0);
        VM4;        // completes t1's 4 half-tiles; t2 B pair stays in flight
        SBAR;
        // ---- K-tile t+1 (buf1) ----
        LOADA(1, 0); LOADB(1, b01, 0);
        stageA(0, 0, t2);
        SBAR; LGKM0; MFMA_Q(0, b01, 0); SBAR;
        LOADB(1, b23, 2);
        stageA(0, 1, t2);
        SBAR; LGKM0; MFMA_Q(0, b23, 2); SBAR;
        LOADA(1, 4);
        stageB(1, 0, t3);
        SBAR; LGKM0; MFMA_Q(4, b23, 2); SBAR;
        stageB(1, 1, t3);
        SBAR; MFMA_Q(4, b01, 0);
        VM4;        // completes t2's 4 half-tiles; t3 B pair stays in flight
        SBAR;
    }

    // drain tail prefetches before epilogue / endpgm
    asm volatile("s_waitcnt vmcnt(0)" ::: "memory");
    SBAR;

#undef LOADA
#undef LOADB
#undef MFMA_Q
#undef SBAR
#undef LGKM0
#undef VM4

    // C/D layout: col = lane&15, row = (lane>>4)*4 + reg
    #pragma unroll
    for (int i = 0; i < 8; ++i) {
        #pragma unroll
        for (int j = 0; j < 4; ++j) {
            const int rowb = row0 + wm * 128 + i * 16 + fq * 4;
            const int col  = col0 + wn * 64 + j * 16 + fl;
            const float badd = bias ? bias[col] : 0.0f;
            if (transC) {
                // vT[b][o][n] = [8][256][2048]; rowb..rowb+3 within one batch
                bf16x4 o;
                #pragma unroll
                for (int r = 0; r < 4; ++r)
                    o[r] = bfbits(acc[i][j][r] * scale + badd);
                *(bf16x4*)(Cb + (size_t)(rowb >> 11) * ND +
                           (size_t)col * SEQ + (rowb & 2047)) = o;
            } else {
                #pragma unroll
                for (int r = 0; r < 4; ++r) {
                    const int row = rowb + r;
                    const float val = acc[i][j][r] * scale + badd;
                    if (Cf) Cf[(size_t)row * Ncols + col] = val;
                    if (Cb) Cb[(size_t)row * Ncols + col] = __float2bfloat16(val);
                }
            }
        }
    }
}

// ---------------------------------------------------------------------------
// batched square-GEMM wrapper. Supertile mapping for the (8,8,z) grid:
// hw XCD = blockIdx.x (linear dispatch % 8 with gx=8), and XCD x owns a
// 2-row x 4-col supertile of output tiles per batch -> per-XCD/batch
// working set A 2MB + B 4MB (was A 8MB + B 1MB with col-panel mapping).
// Bijective: row=(x&3)*2+(y&1), col=(x>>2)*4+(y>>1).
// ---------------------------------------------------------------------------
__global__ __launch_bounds__(512, 2) void gemm256(
        const bf16* __restrict__ A, const bf16* __restrict__ Bt,
        float* __restrict__ Cf, bf16* __restrict__ Cb,
        int M, int Ncols, int K,
        long long sA, long long sB, long long sCf, long long sCb,
        float scale) {
    (void)M;
    const int bz = blockIdx.z;
    const int x = blockIdx.x, y = blockIdx.y;
    int rt, ct;
    if (gridDim.x == 8 && gridDim.y == 8) {
        rt = (x & 3) * 2 + (y & 1);
        ct = (x >> 2) * 4 + (y >> 1);
    } else {
        rt = x; ct = y;
    }
    const int row0 = rt * 256;
    const int col0 = ct * 256;
    gemm256_body(A + (size_t)bz * sA, Bt + (size_t)bz * sB,
                 Cf ? Cf + (size_t)bz * sCf : nullptr,
                 Cb ? Cb + (size_t)bz * sCb : nullptr,
                 Ncols, K, row0, col0, scale, nullptr, 0);
}

// ---------------------------------------------------------------------------
// fused QKV projection: z selects {Wq,Wk,Wv}; v written transposed to vT.
// ---------------------------------------------------------------------------
__global__ __launch_bounds__(512, 2) void qkv256(
        const bf16* __restrict__ textb,
        const bf16* __restrict__ WqT, const bf16* __restrict__ WkT,
        const bf16* __restrict__ WvT,
        const float* __restrict__ bq, const float* __restrict__ bk,
        const float* __restrict__ bv,
        bf16* __restrict__ q, bf16* __restrict__ k, bf16* __restrict__ vT) {
    const int x = blockIdx.x;                       // 0..63
    const int swz = (x & 7) * 8 + (x >> 3);         // XCD swizzle (64 wgs)
    const int row0 = swz * 256;
    const int z = blockIdx.z;
    const bf16* W = (z == 0) ? WqT : (z == 1) ? WkT : WvT;
    const float* bias = (z == 0) ? bq : (z == 1) ? bk : bv;
    bf16* out = (z == 0) ? q : (z == 1) ? k : vT;
    gemm256_body(textb, W, nullptr, out, DIM, DIM, row0, 0, 1.0f,
                 bias, (z == 2) ? 1 : 0);
}

// ---------------------------------------------------------------------------
// in-place row softmax: ONE WAVE PER ROW (no LDS, no barriers).
// ---------------------------------------------------------------------------
__global__ __launch_bounds__(256) void softmax_rows(bf16* __restrict__ S) {
    const int w    = threadIdx.x >> 6;
    const int lane = threadIdx.x & 63;
    bf16* p = S + ((size_t)blockIdx.x * 4 + w) * SEQ;
    bf16x8 v[4];
    float x[32];
    #pragma unroll
    for (int j = 0; j < 4; ++j) {
        v[j] = *(const bf16x8*)(p + j * 512 + lane * 8);
        #pragma unroll
        for (int e = 0; e < 8; ++e) x[j * 8 + e] = bf2f(v[j][e]);
    }
    float m = x[0];
    #pragma unroll
    for (int i = 1; i < 32; ++i) m = fmaxf(m, x[i]);
    #pragma unroll
    for (int off = 32; off >= 1; off >>= 1) m = fmaxf(m, __shfl_xor(m, off, 64));
    float s = 0.f;
    #pragma unroll
    for (int i = 0; i < 32; ++i) { x[i] = __expf(x[i] - m); s += x[i]; }
    #pragma unroll
    for (int off = 32; off >= 1; off >>= 1) s += __shfl_xor(s, off, 64);
    const float inv = 1.0f / s;
    #pragma unroll
    for (int j = 0; j < 4; ++j) {
        bf16x8 o;
        #pragma unroll
        for (int e = 0; e < 8; ++e) o[e] = bfbits(x[j * 8 + e] * inv);
        *(bf16x8*)(p + j * 512 + lane * 8) = o;
    }
}

// ---------------------------------------------------------------------------
extern "C" void kernel_launch(void* const* d_in, const int* in_sizes, int n_in,
                              void* d_out, int out_size, void* d_ws, size_t ws_size,
                              hipStream_t stream) {
    (void)in_sizes; (void)n_in; (void)out_size; (void)ws_size;
    const float* text = (const float*)d_in[0];
    const float* adj  = (const float*)d_in[1];
    const float* Wq   = (const float*)d_in[2];
    const float* bq   = (const float*)d_in[3];
    const float* Wk   = (const float*)d_in[4];
    const float* bk   = (const float*)d_in[5];
    const float* Wv   = (const float*)d_in[6];
    const float* bv   = (const float*)d_in[7];

    float* out0 = (float*)d_out;                 // output [B,N,D]
    float* out1 = out0 + (size_t)BATCH * ND;     // new_adj [B,N,N]

    bf16* w = (bf16*)d_ws;
    bf16* adjT = w;  w += BATCH * NN;
    bf16* qb   = w;  w += BATCH * ND;
    bf16* kb   = w;  w += BATCH * ND;
    bf16* vTb  = w;  w += BATCH * ND;   // [B][D][N]
    bf16* attn = w;  w += BATCH * NN;   // scores, then softmax in place
    bf16* nadj = w;  w += BATCH * NN;

    // textb + WT alias the head of nadj (dead until the attn@adj GEMM)
    bf16* textb = nadj;                     // [16384][256] bf16 = 8.4 MB
    bf16* WqT = nadj + BATCH * ND;          // 3 x [256][256] bf16
    bf16* WkT = WqT + DIM * DIM;
    bf16* WvT = WkT + DIM * DIM;

    // fused prep: transpose adj (8192 blocks) + cast text (2048) + W^T (48)
    prep_all<<<dim3(10288), 256, 0, stream>>>(
        adj, adjT, text, textb, Wq, Wk, Wv, WqT, WkT, WvT);
    // q/k row-major bf16, v transposed -> vT[b][o][n]; bias fused
    qkv256<<<dim3(64, 1, 3), 512, 0, stream>>>(
        textb, WqT, WkT, WvT, bq, bk, bv, qb, kb, vTb);
    // scores = (q @ k^T) / 16  -> bf16
    gemm256<<<dim3(SEQ / 256, SEQ / 256, BATCH), 512, 0, stream>>>(
        qb, kb, nullptr, attn, SEQ, SEQ, DIM,
        (long long)ND, (long long)ND, 0, (long long)NN, 1.0f / 16.0f);
    softmax_rows<<<dim3(BATCH * SEQ / 4), 256, 0, stream>>>(attn);
    // new_adj = attn @ adj  -> fp32 (d_out) + bf16 (ws)
    gemm256<<<dim3(SEQ / 256, SEQ / 256, BATCH), 512, 0, stream>>>(
        attn, adjT, out1, nadj, SEQ, SEQ, SEQ,
        (long long)NN, (long long)NN, (long long)NN, (long long)NN, 1.0f);
    // output = new_adj @ v  -> fp32 (d_out); 128x64 tile => 512 blocks
    gemm_bt<128, 64, 4, 1><<<dim3(16, 4, BATCH), 256, 0, stream>>>(
        nadj, vTb, out0, nullptr, SEQ, DIM, SEQ,
        (long long)NN, (long long)ND, (long long)ND, 0, 1.0f);
}